// Round 14
// baseline (192.045 us; speedup 1.0000x reference)
//
#include <hip/hip_runtime.h>
#include <hip/hip_bf16.h>

// MultiHeadAttention: B=2, S=2048, D=1024, H=16, DH=64, causal, eval-mode.
// f32 I/O, bf16 MFMA internally.
// R22: attn per-CU load balance. All 1024 blocks are co-resident at t=0
//      (4/CU), so what matters is WHICH four share a CU. Old map put
//      qts {31-a,23-a,15-a,7-a} on CU a*?: per-CU work 52..80 units (21%
//      imbalance -> 27% avg occupancy from idle drained CUs). New bijective
//      map: g=bx&255, k=bx>>8, bh=(g&7)*4+k, a=g>>3, qt=(k&1)?a:31-a.
//      Under round-robin CP placement every CU gets (32-a)+(a+1)+(32-a)
//      +(a+1)=66 units - perfectly balanced. Correctness placement-
//      independent. Rest = R21-exact (best: 185.1us).

typedef short bf16x8 __attribute__((ext_vector_type(8)));
typedef float f32x4  __attribute__((ext_vector_type(4)));
typedef short s16x4  __attribute__((ext_vector_type(4)));

#define BB 2
#define SS 2048
#define DD 1024
#define HH 16
#define DHH 64

__device__ __forceinline__ unsigned short f2bf(float f) {
    unsigned u = __builtin_bit_cast(unsigned, f);
    u += 0x7FFFu + ((u >> 16) & 1u);      // RNE
    return (unsigned short)(u >> 16);
}
__device__ __forceinline__ unsigned short f2bf_trunc(float f) {
    return (unsigned short)(__builtin_bit_cast(unsigned, f) >> 16);
}
__device__ __forceinline__ float max3f(float a, float b, float c) {
    return fmaxf(fmaxf(a, b), c);          // -> v_max3_f32
}
// async 16B global -> LDS (dest = wave-uniform base + lane*16B)
__device__ __forceinline__ void cp16(const unsigned short* g, unsigned short* l) {
    __builtin_amdgcn_global_load_lds(
        (const __attribute__((address_space(1))) unsigned int*)(g),
        (__attribute__((address_space(3))) unsigned int*)(l), 16, 0, 0);
}

// ---------------------------------------------------------------- prep
// blocks [0,4096): x f32 -> bf16.  blocks [4096,5120): W transpose f32->bf16.
__global__ __launch_bounds__(256) void prep(
    const float* __restrict__ x,
    const float* __restrict__ w0, const float* __restrict__ w1,
    const float* __restrict__ w2, const float* __restrict__ w3,
    unsigned short* __restrict__ xbf, unsigned short* __restrict__ wt) {
    __shared__ float tile[64][65];
    const int bid = blockIdx.x;
    const int tid = threadIdx.x;
    if (bid < 4096) {                          // cvt: 4 elems/thread
        int i = (bid * 256 + tid) * 4;
        float4 v = *reinterpret_cast<const float4*>(x + i);
        s16x4 p;
        p[0] = (short)f2bf(v.x); p[1] = (short)f2bf(v.y);
        p[2] = (short)f2bf(v.z); p[3] = (short)f2bf(v.w);
        *reinterpret_cast<s16x4*>(xbf + i) = p;
        return;
    }
    const int tb = bid - 4096;                 // 0..1023
    const int z  = tb >> 8;                    // matrix 0..3
    const int bx = (tb & 15) * 64, by = ((tb >> 4) & 15) * 64;
    const float* src = z == 0 ? w0 : z == 1 ? w1 : z == 2 ? w2 : w3;
    unsigned short* out = wt + (size_t)z * (DD * DD);
    const int tx = tid & 63, ty = tid >> 6;
    #pragma unroll
    for (int i = 0; i < 64; i += 4)
        tile[ty + i][tx] = src[(size_t)(by + ty + i) * DD + bx + tx];
    __syncthreads();
    #pragma unroll
    for (int i = 0; i < 64; i += 4)
        out[(size_t)(bx + ty + i) * DD + by + tx] = f2bf(tile[tx][ty + i]);
}

// ---------------------------------------------------------------- QKV GEMM
// C[4096x3072] = A @ Wt^T (+bias). 128(M)x192(N) tile, BK=64, 4 waves (2x2),
// double-buffered LDS (80KB) => 2 blocks/CU. Grid (16,32) = 512 blocks.
// Flat 2-phase: stage(t+1) at tile top, one compute block (B-frags read
// once), one __syncthreads per K-tile; co-resident block covers the drain.
__global__ __launch_bounds__(256, 2) void gemm_qkv(
    const unsigned short* __restrict__ A, const unsigned short* __restrict__ Wt,
    const float* __restrict__ b0, const float* __restrict__ b1,
    const float* __restrict__ b2,
    unsigned short* __restrict__ d0, unsigned short* __restrict__ d1,
    unsigned short* __restrict__ d2) {
    __shared__ __align__(16) unsigned short As_[2][128 * 64];
    __shared__ __align__(16) unsigned short Bs_[2][192 * 64];

    const int tid  = threadIdx.x;
    const int lane = tid & 63;
    const int w    = tid >> 6;                 // 0..3
    const int col  = lane & 15;
    const int quad = lane >> 4;
    const int wm   = (w >> 1) * 64;            // M half (64 wide)
    const int wn   = (w & 1) * 96;             // N half (96 wide)
    const int mb   = blockIdx.y * 128;
    const int nb   = blockIdx.x * 192;

    const int r8 = lane >> 3, gg = lane & 7;
    const int srcoff = ((gg ^ r8) * 8);          // source k-group swizzle
    const int cswz = col & 7;                    // frag-read unswizzle key
    const int pos0 = (quad       ^ cswz) * 8;
    const int pos1 = ((4 + quad) ^ cswz) * 8;

    f32x4 acc[4][6];
    #pragma unroll
    for (int i = 0; i < 4; i++)
        #pragma unroll
        for (int j = 0; j < 6; j++) acc[i][j] = (f32x4){0.f, 0.f, 0.f, 0.f};

    // stage one K-tile (128x64 A + 192x64 B): 10 cp16/thread
    auto stage = [&](int b, int kt) {
        #pragma unroll
        for (int i = 0; i < 4; i++) {          // A rows w*32 + i*8 + r8
            int rb = w * 32 + i * 8;
            cp16(A + (size_t)(mb + rb + r8) * 1024 + kt + srcoff,
                 As_[b] + rb * 64);
        }
        #pragma unroll
        for (int i = 0; i < 6; i++) {          // B rows w*48 + i*8 + r8
            int rb = w * 48 + i * 8;
            cp16(Wt + (size_t)(nb + rb + r8) * 1024 + kt + srcoff,
                 Bs_[b] + rb * 64);
        }
    };

    int cur = 0;
    stage(0, 0);
    __syncthreads();                           // tile 0 ready

    for (int kt = 0; kt < 1024; kt += 64) {
        if (kt + 64 < 1024) stage(cur ^ 1, kt + 64);   // issue next-tile loads
        const unsigned short* Ab = As_[cur];
        const unsigned short* Bb = Bs_[cur];
        bf16x8 bq0[6], bq1[6];                 // B-frags: read ONCE per tile
        #pragma unroll
        for (int j = 0; j < 6; j++) {
            const unsigned short* bp = Bb + (wn + j * 16 + col) * 64;
            bq0[j] = *reinterpret_cast<const bf16x8*>(bp + pos0);
            bq1[j] = *reinterpret_cast<const bf16x8*>(bp + pos1);
        }
        #pragma unroll
        for (int mi = 0; mi < 4; mi++) {
            const unsigned short* ap = Ab + (wm + mi * 16 + col) * 64;
            bf16x8 a0 = *reinterpret_cast<const bf16x8*>(ap + pos0);
            bf16x8 a1 = *reinterpret_cast<const bf16x8*>(ap + pos1);
            #pragma unroll
            for (int j = 0; j < 6; j++) {
                acc[mi][j] = __builtin_amdgcn_mfma_f32_16x16x32_bf16(a0, bq0[j], acc[mi][j], 0, 0, 0);
                acc[mi][j] = __builtin_amdgcn_mfma_f32_16x16x32_bf16(a1, bq1[j], acc[mi][j], 0, 0, 0);
            }
        }
        __syncthreads();                       // drain next-tile loads + WAR
        cur ^= 1;
    }

    const float QSCALE = 0.125f * 1.44269504f;   // 1/sqrt(DH) * log2(e)
    #pragma unroll
    for (int mi = 0; mi < 4; mi++) {
        int mg = mb + wm + mi * 16 + quad * 4;     // C row = quad*4+reg
        #pragma unroll
        for (int nj = 0; nj < 6; nj++) {
            int ng = nb + wn + nj * 16 + col;      // C col = lane&15
            int sel = ng >> 10, n2 = ng & 1023;
            int h = n2 >> 6, dd2 = n2 & 63;
            int b = mg >> 11, s = mg & 2047;
            int bh = b * HH + h;
            const float* bp = sel == 0 ? b0 : sel == 1 ? b1 : b2;
            float bbv = bp[n2];
            if (sel == 0) {          // Q (pre-scaled for exp2 softmax)
                #pragma unroll
                for (int r = 0; r < 4; r++)
                    d0[((size_t)bh * SS + s + r) * DHH + dd2] = f2bf((acc[mi][nj][r] + bbv) * QSCALE);
            } else if (sel == 1) {   // K
                #pragma unroll
                for (int r = 0; r < 4; r++)
                    d1[((size_t)bh * SS + s + r) * DHH + dd2] = f2bf(acc[mi][nj][r] + bbv);
            } else {                 // V^T [b][h][d][s]
                s16x4 pack;
                #pragma unroll
                for (int r = 0; r < 4; r++) pack[r] = (short)f2bf(acc[mi][nj][r] + bbv);
                *reinterpret_cast<s16x4*>(d2 + ((size_t)bh * DHH + dd2) * SS + s) = pack;
            }
        }
    }
}

// ---------------------------------------------------------------- out GEMM
// C[4096x1024] = A @ Wt^T + b, f32 out. 128x128 tile, BK=64, 4 waves (2x2),
// double-buffered (64KB), minimal 2-phase, XCD-swizzled. Grid 256 = 1/CU.
__global__ __launch_bounds__(256) void gemm_out(
    const unsigned short* __restrict__ A, const unsigned short* __restrict__ Wt,
    const float* __restrict__ b0, float* __restrict__ d0f) {
    __shared__ __align__(16) unsigned short As_[2][128 * 64];
    __shared__ __align__(16) unsigned short Bs_[2][128 * 64];

    const int tid  = threadIdx.x;
    const int lane = tid & 63;
    const int w    = tid >> 6;
    const int col  = lane & 15;
    const int quad = lane >> 4;
    const int wm   = (w >> 1) * 64;
    const int wn   = (w & 1) * 64;

    // T1 swizzle: grid (8,32) flat 0..255
    const int flat = blockIdx.y * 8 + blockIdx.x;
    const int swz  = (flat & 7) * 32 + (flat >> 3);
    const int mb   = (swz >> 3) * 128;
    const int nb   = (swz & 7) * 128;

    const int r8 = lane >> 3, gg = lane & 7;
    const int srcoff = ((gg ^ r8) * 8);
    const int cswz = col & 7;
    const int pos0 = (quad       ^ cswz) * 8;
    const int pos1 = ((4 + quad) ^ cswz) * 8;

    f32x4 acc[4][4];
    #pragma unroll
    for (int i = 0; i < 4; i++)
        #pragma unroll
        for (int j = 0; j < 4; j++) acc[i][j] = (f32x4){0.f, 0.f, 0.f, 0.f};

    auto stage = [&](int b, int kt) {
        #pragma unroll
        for (int it = 0; it < 4; it++) {
            int row = w * 32 + it * 8;
            cp16(A  + (size_t)(mb + row + r8) * 1024 + kt + srcoff, As_[b] + row * 64);
            cp16(Wt + (size_t)(nb + row + r8) * 1024 + kt + srcoff, Bs_[b] + row * 64);
        }
    };

    int cur = 0;
    stage(0, 0);
    __syncthreads();

    for (int kt = 0; kt < 1024; kt += 64) {
        if (kt + 64 < 1024) stage(cur ^ 1, kt + 64);
        const unsigned short* Ab = As_[cur];
        const unsigned short* Bb = Bs_[cur];
        bf16x8 bq0[4], bq1[4];                 // B-frags once per tile
        #pragma unroll
        for (int j = 0; j < 4; j++) {
            const unsigned short* bp = Bb + (wn + j * 16 + col) * 64;
            bq0[j] = *reinterpret_cast<const bf16x8*>(bp + pos0);
            bq1[j] = *reinterpret_cast<const bf16x8*>(bp + pos1);
        }
        #pragma unroll
        for (int i = 0; i < 4; i++) {
            const unsigned short* ap = Ab + (wm + i * 16 + col) * 64;
            bf16x8 a0 = *reinterpret_cast<const bf16x8*>(ap + pos0);
            bf16x8 a1 = *reinterpret_cast<const bf16x8*>(ap + pos1);
            #pragma unroll
            for (int j = 0; j < 4; j++) {
                acc[i][j] = __builtin_amdgcn_mfma_f32_16x16x32_bf16(a0, bq0[j], acc[i][j], 0, 0, 0);
                acc[i][j] = __builtin_amdgcn_mfma_f32_16x16x32_bf16(a1, bq1[j], acc[i][j], 0, 0, 0);
            }
        }
        __syncthreads();
        cur ^= 1;
    }

    #pragma unroll
    for (int i = 0; i < 4; i++) {
        int mg = mb + wm + i * 16 + quad * 4;
        #pragma unroll
        for (int j = 0; j < 4; j++) {
            int ng = nb + wn + j * 16 + col;
            float bbv = b0[ng];
            #pragma unroll
            for (int r = 0; r < 4; r++)
                d0f[(size_t)(mg + r) * 1024 + ng] = acc[i][j][r] + bbv;
        }
    }
}

// ---------------------------------------------------------------- attention
// 1024 blocks, work-balanced remap: g=bx&255, k=bx>>8, bh=(g&7)*4+k,
// a=g>>3, qt=(k&1)?a:31-a. Bijective over (bh,qt); under round-robin CP
// placement every CU's 4 blocks sum to 66 tile-units (was 52..80).
// 4 waves x 16 q-rows. Swapped QK^T with C init = -m_i (defer-max THR=8).
// K staged bit-permuted so QK C-layout regs are exactly PV's A-frag
// layout. Row-max via max3 tree. 32KB LDS, 4 blk/CU, 2 barriers/pair.
__global__ __launch_bounds__(256, 4) void attn(
    const unsigned short* __restrict__ Q, const unsigned short* __restrict__ K,
    const unsigned short* __restrict__ Vt, unsigned short* __restrict__ O) {
    __shared__ __align__(16) unsigned short Ks[2][64 * 64];  // [perm key][dh] swizzled
    __shared__ __align__(16) unsigned short Vs[2][64 * 64];  // [dh][key] swizzled

    const int tid  = threadIdx.x;
    const int lane = tid & 63;
    const int w    = tid >> 6;
    const int col  = lane & 15;
    const int quad = lane >> 4;
    // work-balanced bijective (bh, qt) remap
    const int gmap = blockIdx.x & 255;
    const int kmap = blockIdx.x >> 8;
    const int bh   = (gmap & 7) * 4 + kmap;
    const int amap = gmap >> 3;
    const int qt   = (kmap & 1) ? amap : 31 - amap;
    const int qb   = qt * 64;
    const int r8 = lane >> 3, gg = lane & 7;
    const int srcoff = ((gg ^ r8) * 8);
    const int cswz = col & 7;
    const int pos0 = (quad       ^ cswz) * 8;  // loop-invariant frag offsets
    const int pos1 = ((4 + quad) ^ cswz) * 8;

    bf16x8 onesf;                               // B-frag: virtual V col of 1s
    #pragma unroll
    for (int j = 0; j < 8; j++) onesf[j] = (col == 0) ? (short)0x3F80 : (short)0;

    const int qrow = qb + w * 16 + col;         // this lane's q-row (= C col)
    const size_t qbase = ((size_t)bh * SS + qrow) * DHH;
    bf16x8 qlo = *reinterpret_cast<const bf16x8*>(Q + qbase + quad * 8);
    bf16x8 qhi = *reinterpret_cast<const bf16x8*>(Q + qbase + 32 + quad * 8);

    f32x4 o[5];
    #pragma unroll
    for (int d = 0; d < 5; d++) o[d] = (f32x4){0.f, 0.f, 0.f, 0.f};
    float m_i = 0.0f;                           // deferred running max (log2)

    const int ntiles = qt + 1;
    for (int t0 = 0; t0 < ntiles; t0 += 2) {
        const bool two = (t0 + 1 < ntiles);
        __syncthreads();                       // WAR on Ks/Vs
        #pragma unroll
        for (int it = 0; it < 2; it++) {       // stage sub0: K(permuted) + V^T
            int drow = w * 16 + it * 8;        // LDS dest base (uniform)
            int skey = (w >> 1) * 32 + it * 16 + (r8 >> 2) * 8 + (w & 1) * 4 + (r8 & 3);
            cp16(K  + ((size_t)bh * SS + t0 * 64 + skey) * DHH + srcoff,
                 Ks[0] + drow * 64);
            cp16(Vt + ((size_t)bh * DHH + drow + r8) * SS + t0 * 64 + srcoff,
                 Vs[0] + drow * 64);
        }
        if (two) {
            #pragma unroll
            for (int it = 0; it < 2; it++) {   // stage sub1
                int drow = w * 16 + it * 8;
                int skey = (w >> 1) * 32 + it * 16 + (r8 >> 2) * 8 + (w & 1) * 4 + (r8 & 3);
                cp16(K  + ((size_t)bh * SS + (t0 + 1) * 64 + skey) * DHH + srcoff,
                     Ks[1] + drow * 64);
                cp16(Vt + ((size_t)bh * DHH + drow + r8) * SS + (t0 + 1) * 64 + srcoff,
                     Vs[1] + drow * 64);
            }
        }
        __syncthreads();

        // ---- scores: swapped operands; C init = -m_i folds the max shift
        const float negm = -m_i;
        const f32x4 zinit = (f32x4){negm, negm, negm, negm};
        f32x4 sc[8];
        #pragma unroll
        for (int nt = 0; nt < 4; nt++) {
            int krow = nt * 16 + col;
            bf16x8 klo = *reinterpret_cast<const bf16x8*>(Ks[0] + krow * 64 + pos0);
            bf16x8 khi = *reinterpret_cast<const bf16x8*>(Ks[0] + krow * 64 + pos1);
            f32x4 z = zinit;
            z = __builtin_amdgcn_mfma_f32_16x16x32_bf16(klo, qlo, z, 0, 0, 0);
            z = __builtin_amdgcn_mfma_f32_16x16x32_bf16(khi, qhi, z, 0, 0, 0);
            sc[nt] = z;
        }
        if (two) {
            #pragma unroll
            for (int nt = 0; nt < 4; nt++) {
                int krow = nt * 16 + col;
                bf16x8 klo = *reinterpret_cast<const bf16x8*>(Ks[1] + krow * 64 + pos0);
                bf16x8 khi = *reinterpret_cast<const bf16x8*>(Ks[1] + krow * 64 + pos1);
                f32x4 z = zinit;
                z = __builtin_amdgcn_mfma_f32_16x16x32_bf16(klo, qlo, z, 0, 0, 0);
                z = __builtin_amdgcn_mfma_f32_16x16x32_bf16(khi, qhi, z, 0, 0, 0);
                sc[4 + nt] = z;
            }
        }
        // causal mask (diagonal tile only; t0==qt implies !two).
        // sc[sb+nt][r] covers key = tb*64 + (nt>>1)*32 + quad*8 + (nt&1)*4 + r.
        if (t0 == qt || (two && t0 + 1 == qt)) {
            const int sb = (t0 == qt) ? 0 : 4;
            const int tb = (t0 == qt) ? t0 : t0 + 1;
            #pragma unroll
            for (int nt = 0; nt < 4; nt++) {
                #pragma unroll
                for (int r = 0; r < 4; r++) {
                    int kg = tb * 64 + (nt >> 1) * 32 + quad * 8 + (nt & 1) * 4 + r;
                    if (kg > qrow) sc[sb + nt][r] = -3.0e38f;
                }
            }
        }
        // ---- overflow check (defer-max THR=8); max3-form reduction
        float mx;
        {
            float a0 = max3f(sc[0][0], sc[0][1], sc[0][2]);
            float a1 = max3f(sc[0][3], sc[1][0], sc[1][1]);
            float a2 = max3f(sc[1][2], sc[1][3], sc[2][0]);
            float a3 = max3f(sc[2][1], sc[2][2], sc[2][3]);
            float a4 = max3f(sc[3][0], sc[3][1], sc[3][2]);
            float b0v = max3f(a0, a1, a2);
            float b1v = max3f(a3, a4, sc[3][3]);
            mx = fmaxf(b0v, b1v);
        }
        if (two) {
            float c0 = max3f(sc[4][0], sc[4][1], sc[4][2]);
            float c1 = max3f(sc[4][3], sc[5][0], sc[5][1]);
            float c2 = max3f(sc[5][2], sc[5][3], sc[6][0]);
            float c3 = max3f(sc[6][1], sc[6][2], sc[6][3]);
            float c4 = max3f(sc[7][0], sc[7][1], sc[7][2]);
            float d0v = max3f(c0, c1, c2);
            float d1v = max3f(c3, c4, sc[7][3]);
            mx = max3f(mx, d0v, d1v);
        }
        mx = fmaxf(mx, __shfl_xor(mx, 16));     // unify across the 4 lanes
        mx = fmaxf(mx, __shfl_xor(mx, 32));     // sharing this q-row
        if (__any(mx > 8.0f)) {                 // rare: headroom exceeded
            float dlt = (mx > 8.0f) ? mx : 0.0f;  // per q-row shift
            m_i += dlt;
            #pragma unroll
            for (int nt = 0; nt < 4; nt++)
                #pragma unroll
                for (int r = 0; r < 4; r++) sc[nt][r] -= dlt;
            if (two) {
                #pragma unroll
                for (int nt = 4; nt < 8; nt++)
                    #pragma unroll
                    for (int r = 0; r < 4; r++) sc[nt][r] -= dlt;
            }
            #pragma unroll
            for (int r = 0; r < 4; r++) {       // rescale o rows quad*4+r
                float a = exp2f(-__shfl(dlt, quad * 4 + r));
                #pragma unroll
                for (int d = 0; d < 5; d++) o[d][r] *= a;
            }
        }

        // ---- sub0: P = exp2(sc) in-register (already A-frag order) + PV
        {
            bf16x8 pf0, pf1;
            #pragma unroll
            for (int j = 0; j < 8; j++) {
                pf0[j] = (short)f2bf_trunc(exp2f(sc[(j >> 2)][j & 3]));
                pf1[j] = (short)f2bf_trunc(exp2f(sc[2 + (j >> 2)][j & 3]));
            }
            #pragma unroll
            for (int dt = 0; dt < 4; dt++) {
                int rv = dt * 16 + col;
                bf16x8 vf0 = *reinterpret_cast<const bf16x8*>(Vs[0] + rv * 64 + pos0);
                bf16x8 vf1 = *reinterpret_cast<const bf16x8*>(Vs[0] + rv * 64 + pos1);
                o[dt] = __builtin_amdgcn_mfma_f32_16x16x32_bf16(pf0, vf0, o[dt], 0, 0, 0);
                o[dt] = __builtin_amdgcn_mfma_f32_16x16x32_bf16(pf1, vf1, o[dt], 0, 0, 0);
            }
            o[4] = __builtin_amdgcn_mfma_f32_16x16x32_bf16(pf0, onesf, o[4], 0, 0, 0);
            o[4] = __builtin_amdgcn_mfma_f32_16x16x32_bf16(pf1, onesf, o[4], 0, 0, 0);
        }
        // ---- sub1
        if (two) {
            bf16x8 pf0, pf1;
            #pragma unroll
            for (int j = 0; j < 8; j++) {
                pf0[j] = (short)f2bf_trunc(exp2f(sc[4 + (j >> 2)][j & 3]));
                pf1[j] = (short)f2bf_trunc(exp2f(sc[6 + (j >> 2)][j & 3]));
            }
            #pragma unroll
            for (int dt = 0; dt < 4; dt++) {
                int rv = dt * 16 + col;
                bf16x8 vf0 = *reinterpret_cast<const bf16x8*>(Vs[1] + rv * 64 + pos0);
                bf16x8 vf1 = *reinterpret_cast<const bf16x8*>(Vs[1] + rv * 64 + pos1);
                o[dt] = __builtin_amdgcn_mfma_f32_16x16x32_bf16(pf0, vf0, o[dt], 0, 0, 0);
                o[dt] = __builtin_amdgcn_mfma_f32_16x16x32_bf16(pf1, vf1, o[dt], 0, 0, 0);
            }
            o[4] = __builtin_amdgcn_mfma_f32_16x16x32_bf16(pf0, onesf, o[4], 0, 0, 0);
            o[4] = __builtin_amdgcn_mfma_f32_16x16x32_bf16(pf1, onesf, o[4], 0, 0, 0);
        }
    }

    // epilogue: l lives in o[4][r] of lanes col==0; broadcast within quad
    #pragma unroll
    for (int r = 0; r < 4; r++) {
        float lv = __shfl(o[4][r], lane & 48);
        float inv = 1.0f / lv;
        int sq = qb + w * 16 + quad * 4 + r;
        size_t base = ((size_t)(bh >> 4) * SS + sq) * DD + (size_t)(bh & 15) * DHH;
        #pragma unroll
        for (int dt = 0; dt < 4; dt++)
            O[base + dt * 16 + col] = f2bf(o[dt][r] * inv);
    }
}

// ---------------------------------------------------------------- launch
extern "C" void kernel_launch(void* const* d_in, const int* in_sizes, int n_in,
                              void* d_out, int out_size, void* d_ws, size_t ws_size,
                              hipStream_t stream) {
    (void)in_sizes; (void)n_in; (void)out_size; (void)ws_size;
    const float* x  = (const float*)d_in[0];
    const float* Wq = (const float*)d_in[2];
    const float* bq = (const float*)d_in[3];
    const float* Wk = (const float*)d_in[4];
    const float* bk = (const float*)d_in[5];
    const float* Wv = (const float*)d_in[6];
    const float* bv = (const float*)d_in[7];
    const float* Wo = (const float*)d_in[8];
    const float* bo = (const float*)d_in[9];
    float* out = (float*)d_out;

    // ws (40 MB): x_bf/O | Q | K | V^T | Wt x4
    char* ws = (char*)d_ws;
    unsigned short* xbf = (unsigned short*)(ws);
    unsigned short* qws = (unsigned short*)(ws + ((size_t)8  << 20));
    unsigned short* kws = (unsigned short*)(ws + ((size_t)16 << 20));
    unsigned short* vws = (unsigned short*)(ws + ((size_t)24 << 20));
    unsigned short* wt  = (unsigned short*)(ws + ((size_t)32 << 20));
    unsigned short* ows = xbf;   // O overwrites x_bf (dead after QKV GEMM)

    prep<<<dim3(5120), 256, 0, stream>>>(x, Wq, Wk, Wv, Wo, xbf, wt);
    gemm_qkv<<<dim3(16, 32), 256, 0, stream>>>(xbf, wt, bq, bk, bv,
                                               qws, kws, vws);
    attn<<<dim3(1024), 256, 0, stream>>>(qws, kws, vws, ows);
    gemm_out<<<dim3(8, 32), 256, 0, stream>>>(ows, wt + (size_t)3 * 1024 * 1024,
                                              bo, out);
}

// Round 15
// 184.759 us; speedup vs baseline: 1.0394x; 1.0394x over previous
//
#include <hip/hip_runtime.h>
#include <hip/hip_bf16.h>

// MultiHeadAttention: B=2, S=2048, D=1024, H=16, DH=64, causal, eval-mode.
// f32 I/O, bf16 MFMA internally.
// R23: exact revert to R21 (measured best: 185.1us). R22's balanced block
//      remap REGRESSED (43.2->45.8: occupancy fell to 22%, FETCH/WRITE
//      rose - CP placement is not round-robin, and bh=bx&31's stride-32
//      same-head pattern had better per-XCD KV L2 locality). Block-remap
//      theories on this machine require within-probe A/B; two failed now
//      (R14 qkv T1, R22 attn balance). This locks in the best config:
//      attn = swapped-QK + defer-max/m-fold + max3 tree, 32KB/4blk-CU;
//      gemm_qkv = 128x192 dbuf 2blk/CU; gemm_out = 128x128 dbuf+swizzle.

typedef short bf16x8 __attribute__((ext_vector_type(8)));
typedef float f32x4  __attribute__((ext_vector_type(4)));
typedef short s16x4  __attribute__((ext_vector_type(4)));

#define BB 2
#define SS 2048
#define DD 1024
#define HH 16
#define DHH 64

__device__ __forceinline__ unsigned short f2bf(float f) {
    unsigned u = __builtin_bit_cast(unsigned, f);
    u += 0x7FFFu + ((u >> 16) & 1u);      // RNE
    return (unsigned short)(u >> 16);
}
__device__ __forceinline__ unsigned short f2bf_trunc(float f) {
    return (unsigned short)(__builtin_bit_cast(unsigned, f) >> 16);
}
__device__ __forceinline__ float max3f(float a, float b, float c) {
    return fmaxf(fmaxf(a, b), c);          // -> v_max3_f32
}
// async 16B global -> LDS (dest = wave-uniform base + lane*16B)
__device__ __forceinline__ void cp16(const unsigned short* g, unsigned short* l) {
    __builtin_amdgcn_global_load_lds(
        (const __attribute__((address_space(1))) unsigned int*)(g),
        (__attribute__((address_space(3))) unsigned int*)(l), 16, 0, 0);
}

// ---------------------------------------------------------------- prep
// blocks [0,4096): x f32 -> bf16.  blocks [4096,5120): W transpose f32->bf16.
__global__ __launch_bounds__(256) void prep(
    const float* __restrict__ x,
    const float* __restrict__ w0, const float* __restrict__ w1,
    const float* __restrict__ w2, const float* __restrict__ w3,
    unsigned short* __restrict__ xbf, unsigned short* __restrict__ wt) {
    __shared__ float tile[64][65];
    const int bid = blockIdx.x;
    const int tid = threadIdx.x;
    if (bid < 4096) {                          // cvt: 4 elems/thread
        int i = (bid * 256 + tid) * 4;
        float4 v = *reinterpret_cast<const float4*>(x + i);
        s16x4 p;
        p[0] = (short)f2bf(v.x); p[1] = (short)f2bf(v.y);
        p[2] = (short)f2bf(v.z); p[3] = (short)f2bf(v.w);
        *reinterpret_cast<s16x4*>(xbf + i) = p;
        return;
    }
    const int tb = bid - 4096;                 // 0..1023
    const int z  = tb >> 8;                    // matrix 0..3
    const int bx = (tb & 15) * 64, by = ((tb >> 4) & 15) * 64;
    const float* src = z == 0 ? w0 : z == 1 ? w1 : z == 2 ? w2 : w3;
    unsigned short* out = wt + (size_t)z * (DD * DD);
    const int tx = tid & 63, ty = tid >> 6;
    #pragma unroll
    for (int i = 0; i < 64; i += 4)
        tile[ty + i][tx] = src[(size_t)(by + ty + i) * DD + bx + tx];
    __syncthreads();
    #pragma unroll
    for (int i = 0; i < 64; i += 4)
        out[(size_t)(bx + ty + i) * DD + by + tx] = f2bf(tile[tx][ty + i]);
}

// ---------------------------------------------------------------- QKV GEMM
// C[4096x3072] = A @ Wt^T (+bias). 128(M)x192(N) tile, BK=64, 4 waves (2x2),
// double-buffered LDS (80KB) => 2 blocks/CU. Grid (16,32) = 512 blocks.
// Flat 2-phase: stage(t+1) at tile top, one compute block (B-frags read
// once), one __syncthreads per K-tile; co-resident block covers the drain.
__global__ __launch_bounds__(256, 2) void gemm_qkv(
    const unsigned short* __restrict__ A, const unsigned short* __restrict__ Wt,
    const float* __restrict__ b0, const float* __restrict__ b1,
    const float* __restrict__ b2,
    unsigned short* __restrict__ d0, unsigned short* __restrict__ d1,
    unsigned short* __restrict__ d2) {
    __shared__ __align__(16) unsigned short As_[2][128 * 64];
    __shared__ __align__(16) unsigned short Bs_[2][192 * 64];

    const int tid  = threadIdx.x;
    const int lane = tid & 63;
    const int w    = tid >> 6;                 // 0..3
    const int col  = lane & 15;
    const int quad = lane >> 4;
    const int wm   = (w >> 1) * 64;            // M half (64 wide)
    const int wn   = (w & 1) * 96;             // N half (96 wide)
    const int mb   = blockIdx.y * 128;
    const int nb   = blockIdx.x * 192;

    const int r8 = lane >> 3, gg = lane & 7;
    const int srcoff = ((gg ^ r8) * 8);          // source k-group swizzle
    const int cswz = col & 7;                    // frag-read unswizzle key
    const int pos0 = (quad       ^ cswz) * 8;
    const int pos1 = ((4 + quad) ^ cswz) * 8;

    f32x4 acc[4][6];
    #pragma unroll
    for (int i = 0; i < 4; i++)
        #pragma unroll
        for (int j = 0; j < 6; j++) acc[i][j] = (f32x4){0.f, 0.f, 0.f, 0.f};

    // stage one K-tile (128x64 A + 192x64 B): 10 cp16/thread
    auto stage = [&](int b, int kt) {
        #pragma unroll
        for (int i = 0; i < 4; i++) {          // A rows w*32 + i*8 + r8
            int rb = w * 32 + i * 8;
            cp16(A + (size_t)(mb + rb + r8) * 1024 + kt + srcoff,
                 As_[b] + rb * 64);
        }
        #pragma unroll
        for (int i = 0; i < 6; i++) {          // B rows w*48 + i*8 + r8
            int rb = w * 48 + i * 8;
            cp16(Wt + (size_t)(nb + rb + r8) * 1024 + kt + srcoff,
                 Bs_[b] + rb * 64);
        }
    };

    int cur = 0;
    stage(0, 0);
    __syncthreads();                           // tile 0 ready

    for (int kt = 0; kt < 1024; kt += 64) {
        if (kt + 64 < 1024) stage(cur ^ 1, kt + 64);   // issue next-tile loads
        const unsigned short* Ab = As_[cur];
        const unsigned short* Bb = Bs_[cur];
        bf16x8 bq0[6], bq1[6];                 // B-frags: read ONCE per tile
        #pragma unroll
        for (int j = 0; j < 6; j++) {
            const unsigned short* bp = Bb + (wn + j * 16 + col) * 64;
            bq0[j] = *reinterpret_cast<const bf16x8*>(bp + pos0);
            bq1[j] = *reinterpret_cast<const bf16x8*>(bp + pos1);
        }
        #pragma unroll
        for (int mi = 0; mi < 4; mi++) {
            const unsigned short* ap = Ab + (wm + mi * 16 + col) * 64;
            bf16x8 a0 = *reinterpret_cast<const bf16x8*>(ap + pos0);
            bf16x8 a1 = *reinterpret_cast<const bf16x8*>(ap + pos1);
            #pragma unroll
            for (int j = 0; j < 6; j++) {
                acc[mi][j] = __builtin_amdgcn_mfma_f32_16x16x32_bf16(a0, bq0[j], acc[mi][j], 0, 0, 0);
                acc[mi][j] = __builtin_amdgcn_mfma_f32_16x16x32_bf16(a1, bq1[j], acc[mi][j], 0, 0, 0);
            }
        }
        __syncthreads();                       // drain next-tile loads + WAR
        cur ^= 1;
    }

    const float QSCALE = 0.125f * 1.44269504f;   // 1/sqrt(DH) * log2(e)
    #pragma unroll
    for (int mi = 0; mi < 4; mi++) {
        int mg = mb + wm + mi * 16 + quad * 4;     // C row = quad*4+reg
        #pragma unroll
        for (int nj = 0; nj < 6; nj++) {
            int ng = nb + wn + nj * 16 + col;      // C col = lane&15
            int sel = ng >> 10, n2 = ng & 1023;
            int h = n2 >> 6, dd2 = n2 & 63;
            int b = mg >> 11, s = mg & 2047;
            int bh = b * HH + h;
            const float* bp = sel == 0 ? b0 : sel == 1 ? b1 : b2;
            float bbv = bp[n2];
            if (sel == 0) {          // Q (pre-scaled for exp2 softmax)
                #pragma unroll
                for (int r = 0; r < 4; r++)
                    d0[((size_t)bh * SS + s + r) * DHH + dd2] = f2bf((acc[mi][nj][r] + bbv) * QSCALE);
            } else if (sel == 1) {   // K
                #pragma unroll
                for (int r = 0; r < 4; r++)
                    d1[((size_t)bh * SS + s + r) * DHH + dd2] = f2bf(acc[mi][nj][r] + bbv);
            } else {                 // V^T [b][h][d][s]
                s16x4 pack;
                #pragma unroll
                for (int r = 0; r < 4; r++) pack[r] = (short)f2bf(acc[mi][nj][r] + bbv);
                *reinterpret_cast<s16x4*>(d2 + ((size_t)bh * DHH + dd2) * SS + s) = pack;
            }
        }
    }
}

// ---------------------------------------------------------------- out GEMM
// C[4096x1024] = A @ Wt^T + b, f32 out. 128x128 tile, BK=64, 4 waves (2x2),
// double-buffered (64KB), minimal 2-phase, XCD-swizzled. Grid 256 = 1/CU.
__global__ __launch_bounds__(256) void gemm_out(
    const unsigned short* __restrict__ A, const unsigned short* __restrict__ Wt,
    const float* __restrict__ b0, float* __restrict__ d0f) {
    __shared__ __align__(16) unsigned short As_[2][128 * 64];
    __shared__ __align__(16) unsigned short Bs_[2][128 * 64];

    const int tid  = threadIdx.x;
    const int lane = tid & 63;
    const int w    = tid >> 6;
    const int col  = lane & 15;
    const int quad = lane >> 4;
    const int wm   = (w >> 1) * 64;
    const int wn   = (w & 1) * 64;

    // T1 swizzle: grid (8,32) flat 0..255
    const int flat = blockIdx.y * 8 + blockIdx.x;
    const int swz  = (flat & 7) * 32 + (flat >> 3);
    const int mb   = (swz >> 3) * 128;
    const int nb   = (swz & 7) * 128;

    const int r8 = lane >> 3, gg = lane & 7;
    const int srcoff = ((gg ^ r8) * 8);
    const int cswz = col & 7;
    const int pos0 = (quad       ^ cswz) * 8;
    const int pos1 = ((4 + quad) ^ cswz) * 8;

    f32x4 acc[4][4];
    #pragma unroll
    for (int i = 0; i < 4; i++)
        #pragma unroll
        for (int j = 0; j < 4; j++) acc[i][j] = (f32x4){0.f, 0.f, 0.f, 0.f};

    auto stage = [&](int b, int kt) {
        #pragma unroll
        for (int it = 0; it < 4; it++) {
            int row = w * 32 + it * 8;
            cp16(A  + (size_t)(mb + row + r8) * 1024 + kt + srcoff, As_[b] + row * 64);
            cp16(Wt + (size_t)(nb + row + r8) * 1024 + kt + srcoff, Bs_[b] + row * 64);
        }
    };

    int cur = 0;
    stage(0, 0);
    __syncthreads();

    for (int kt = 0; kt < 1024; kt += 64) {
        if (kt + 64 < 1024) stage(cur ^ 1, kt + 64);
        const unsigned short* Ab = As_[cur];
        const unsigned short* Bb = Bs_[cur];
        bf16x8 bq0[4], bq1[4];                 // B-frags once per tile
        #pragma unroll
        for (int j = 0; j < 4; j++) {
            const unsigned short* bp = Bb + (wn + j * 16 + col) * 64;
            bq0[j] = *reinterpret_cast<const bf16x8*>(bp + pos0);
            bq1[j] = *reinterpret_cast<const bf16x8*>(bp + pos1);
        }
        #pragma unroll
        for (int i = 0; i < 4; i++) {
            const unsigned short* ap = Ab + (wm + i * 16 + col) * 64;
            bf16x8 a0 = *reinterpret_cast<const bf16x8*>(ap + pos0);
            bf16x8 a1 = *reinterpret_cast<const bf16x8*>(ap + pos1);
            #pragma unroll
            for (int j = 0; j < 4; j++) {
                acc[i][j] = __builtin_amdgcn_mfma_f32_16x16x32_bf16(a0, bq0[j], acc[i][j], 0, 0, 0);
                acc[i][j] = __builtin_amdgcn_mfma_f32_16x16x32_bf16(a1, bq1[j], acc[i][j], 0, 0, 0);
            }
        }
        __syncthreads();
        cur ^= 1;
    }

    #pragma unroll
    for (int i = 0; i < 4; i++) {
        int mg = mb + wm + i * 16 + quad * 4;
        #pragma unroll
        for (int j = 0; j < 4; j++) {
            int ng = nb + wn + j * 16 + col;
            float bbv = b0[ng];
            #pragma unroll
            for (int r = 0; r < 4; r++)
                d0f[(size_t)(mg + r) * 1024 + ng] = acc[i][j][r] + bbv;
        }
    }
}

// ---------------------------------------------------------------- attention
// 1024 blocks: bh = bx&31, qt = 31-(bx>>5) (heavy first). 4 waves x 16 q-rows.
// Swapped QK^T with C init = -m_i (defer-max THR=8): sc = score - m_i free
// from MFMA; P = exp2(sc) directly, bounded by 2^8. m_i update + sc shift +
// o rescale only on the rare __any(mx>8) path. K staged bit-permuted so QK
// C-layout regs are exactly PV's A-frag layout. Row-max via max3-form tree
// (v_max3_f32, 16 ops for 32 values). 32KB LDS, 4 blk/CU, 2 barriers/pair.
__global__ __launch_bounds__(256, 4) void attn(
    const unsigned short* __restrict__ Q, const unsigned short* __restrict__ K,
    const unsigned short* __restrict__ Vt, unsigned short* __restrict__ O) {
    __shared__ __align__(16) unsigned short Ks[2][64 * 64];  // [perm key][dh] swizzled
    __shared__ __align__(16) unsigned short Vs[2][64 * 64];  // [dh][key] swizzled

    const int tid  = threadIdx.x;
    const int lane = tid & 63;
    const int w    = tid >> 6;
    const int col  = lane & 15;
    const int quad = lane >> 4;
    const int bh   = blockIdx.x & 31;
    const int qt   = 31 - (blockIdx.x >> 5);   // heavy first
    const int qb   = qt * 64;
    const int r8 = lane >> 3, gg = lane & 7;
    const int srcoff = ((gg ^ r8) * 8);
    const int cswz = col & 7;
    const int pos0 = (quad       ^ cswz) * 8;  // loop-invariant frag offsets
    const int pos1 = ((4 + quad) ^ cswz) * 8;

    bf16x8 onesf;                               // B-frag: virtual V col of 1s
    #pragma unroll
    for (int j = 0; j < 8; j++) onesf[j] = (col == 0) ? (short)0x3F80 : (short)0;

    const int qrow = qb + w * 16 + col;         // this lane's q-row (= C col)
    const size_t qbase = ((size_t)bh * SS + qrow) * DHH;
    bf16x8 qlo = *reinterpret_cast<const bf16x8*>(Q + qbase + quad * 8);
    bf16x8 qhi = *reinterpret_cast<const bf16x8*>(Q + qbase + 32 + quad * 8);

    f32x4 o[5];
    #pragma unroll
    for (int d = 0; d < 5; d++) o[d] = (f32x4){0.f, 0.f, 0.f, 0.f};
    float m_i = 0.0f;                           // deferred running max (log2)

    const int ntiles = qt + 1;
    for (int t0 = 0; t0 < ntiles; t0 += 2) {
        const bool two = (t0 + 1 < ntiles);
        __syncthreads();                       // WAR on Ks/Vs
        #pragma unroll
        for (int it = 0; it < 2; it++) {       // stage sub0: K(permuted) + V^T
            int drow = w * 16 + it * 8;        // LDS dest base (uniform)
            int skey = (w >> 1) * 32 + it * 16 + (r8 >> 2) * 8 + (w & 1) * 4 + (r8 & 3);
            cp16(K  + ((size_t)bh * SS + t0 * 64 + skey) * DHH + srcoff,
                 Ks[0] + drow * 64);
            cp16(Vt + ((size_t)bh * DHH + drow + r8) * SS + t0 * 64 + srcoff,
                 Vs[0] + drow * 64);
        }
        if (two) {
            #pragma unroll
            for (int it = 0; it < 2; it++) {   // stage sub1
                int drow = w * 16 + it * 8;
                int skey = (w >> 1) * 32 + it * 16 + (r8 >> 2) * 8 + (w & 1) * 4 + (r8 & 3);
                cp16(K  + ((size_t)bh * SS + (t0 + 1) * 64 + skey) * DHH + srcoff,
                     Ks[1] + drow * 64);
                cp16(Vt + ((size_t)bh * DHH + drow + r8) * SS + (t0 + 1) * 64 + srcoff,
                     Vs[1] + drow * 64);
            }
        }
        __syncthreads();

        // ---- scores: swapped operands; C init = -m_i folds the max shift
        const float negm = -m_i;
        const f32x4 zinit = (f32x4){negm, negm, negm, negm};
        f32x4 sc[8];
        #pragma unroll
        for (int nt = 0; nt < 4; nt++) {
            int krow = nt * 16 + col;
            bf16x8 klo = *reinterpret_cast<const bf16x8*>(Ks[0] + krow * 64 + pos0);
            bf16x8 khi = *reinterpret_cast<const bf16x8*>(Ks[0] + krow * 64 + pos1);
            f32x4 z = zinit;
            z = __builtin_amdgcn_mfma_f32_16x16x32_bf16(klo, qlo, z, 0, 0, 0);
            z = __builtin_amdgcn_mfma_f32_16x16x32_bf16(khi, qhi, z, 0, 0, 0);
            sc[nt] = z;
        }
        if (two) {
            #pragma unroll
            for (int nt = 0; nt < 4; nt++) {
                int krow = nt * 16 + col;
                bf16x8 klo = *reinterpret_cast<const bf16x8*>(Ks[1] + krow * 64 + pos0);
                bf16x8 khi = *reinterpret_cast<const bf16x8*>(Ks[1] + krow * 64 + pos1);
                f32x4 z = zinit;
                z = __builtin_amdgcn_mfma_f32_16x16x32_bf16(klo, qlo, z, 0, 0, 0);
                z = __builtin_amdgcn_mfma_f32_16x16x32_bf16(khi, qhi, z, 0, 0, 0);
                sc[4 + nt] = z;
            }
        }
        // causal mask (diagonal tile only; t0==qt implies !two).
        // sc[sb+nt][r] covers key = tb*64 + (nt>>1)*32 + quad*8 + (nt&1)*4 + r.
        if (t0 == qt || (two && t0 + 1 == qt)) {
            const int sb = (t0 == qt) ? 0 : 4;
            const int tb = (t0 == qt) ? t0 : t0 + 1;
            #pragma unroll
            for (int nt = 0; nt < 4; nt++) {
                #pragma unroll
                for (int r = 0; r < 4; r++) {
                    int kg = tb * 64 + (nt >> 1) * 32 + quad * 8 + (nt & 1) * 4 + r;
                    if (kg > qrow) sc[sb + nt][r] = -3.0e38f;
                }
            }
        }
        // ---- overflow check (defer-max THR=8); max3-form reduction
        float mx;
        {
            float a0 = max3f(sc[0][0], sc[0][1], sc[0][2]);
            float a1 = max3f(sc[0][3], sc[1][0], sc[1][1]);
            float a2 = max3f(sc[1][2], sc[1][3], sc[2][0]);
            float a3 = max3f(sc[2][1], sc[2][2], sc[2][3]);
            float a4 = max3f(sc[3][0], sc[3][1], sc[3][2]);
            float b0v = max3f(a0, a1, a2);
            float b1v = max3f(a3, a4, sc[3][3]);
            mx = fmaxf(b0v, b1v);
        }
        if (two) {
            float c0 = max3f(sc[4][0], sc[4][1], sc[4][2]);
            float c1 = max3f(sc[4][3], sc[5][0], sc[5][1]);
            float c2 = max3f(sc[5][2], sc[5][3], sc[6][0]);
            float c3 = max3f(sc[6][1], sc[6][2], sc[6][3]);
            float c4 = max3f(sc[7][0], sc[7][1], sc[7][2]);
            float d0v = max3f(c0, c1, c2);
            float d1v = max3f(c3, c4, sc[7][3]);
            mx = max3f(mx, d0v, d1v);
        }
        mx = fmaxf(mx, __shfl_xor(mx, 16));     // unify across the 4 lanes
        mx = fmaxf(mx, __shfl_xor(mx, 32));     // sharing this q-row
        if (__any(mx > 8.0f)) {                 // rare: headroom exceeded
            float dlt = (mx > 8.0f) ? mx : 0.0f;  // per q-row shift
            m_i += dlt;
            #pragma unroll
            for (int nt = 0; nt < 4; nt++)
                #pragma unroll
                for (int r = 0; r < 4; r++) sc[nt][r] -= dlt;
            if (two) {
                #pragma unroll
                for (int nt = 4; nt < 8; nt++)
                    #pragma unroll
                    for (int r = 0; r < 4; r++) sc[nt][r] -= dlt;
            }
            #pragma unroll
            for (int r = 0; r < 4; r++) {       // rescale o rows quad*4+r
                float a = exp2f(-__shfl(dlt, quad * 4 + r));
                #pragma unroll
                for (int d = 0; d < 5; d++) o[d][r] *= a;
            }
        }

        // ---- sub0: P = exp2(sc) in-register (already A-frag order) + PV
        {
            bf16x8 pf0, pf1;
            #pragma unroll
            for (int j = 0; j < 8; j++) {
                pf0[j] = (short)f2bf_trunc(exp2f(sc[(j >> 2)][j & 3]));
                pf1[j] = (short)f2bf_trunc(exp2f(sc[2 + (j >> 2)][j & 3]));
            }
            #pragma unroll
            for (int dt = 0; dt < 4; dt++) {
                int rv = dt * 16 + col;
                bf16x8 vf0 = *reinterpret_cast<const bf16x8*>(Vs[0] + rv * 64 + pos0);
                bf16x8 vf1 = *reinterpret_cast<const bf16x8*>(Vs[0] + rv * 64 + pos1);
                o[dt] = __builtin_amdgcn_mfma_f32_16x16x32_bf16(pf0, vf0, o[dt], 0, 0, 0);
                o[dt] = __builtin_amdgcn_mfma_f32_16x16x32_bf16(pf1, vf1, o[dt], 0, 0, 0);
            }
            o[4] = __builtin_amdgcn_mfma_f32_16x16x32_bf16(pf0, onesf, o[4], 0, 0, 0);
            o[4] = __builtin_amdgcn_mfma_f32_16x16x32_bf16(pf1, onesf, o[4], 0, 0, 0);
        }
        // ---- sub1
        if (two) {
            bf16x8 pf0, pf1;
            #pragma unroll
            for (int j = 0; j < 8; j++) {
                pf0[j] = (short)f2bf_trunc(exp2f(sc[4 + (j >> 2)][j & 3]));
                pf1[j] = (short)f2bf_trunc(exp2f(sc[6 + (j >> 2)][j & 3]));
            }
            #pragma unroll
            for (int dt = 0; dt < 4; dt++) {
                int rv = dt * 16 + col;
                bf16x8 vf0 = *reinterpret_cast<const bf16x8*>(Vs[1] + rv * 64 + pos0);
                bf16x8 vf1 = *reinterpret_cast<const bf16x8*>(Vs[1] + rv * 64 + pos1);
                o[dt] = __builtin_amdgcn_mfma_f32_16x16x32_bf16(pf0, vf0, o[dt], 0, 0, 0);
                o[dt] = __builtin_amdgcn_mfma_f32_16x16x32_bf16(pf1, vf1, o[dt], 0, 0, 0);
            }
            o[4] = __builtin_amdgcn_mfma_f32_16x16x32_bf16(pf0, onesf, o[4], 0, 0, 0);
            o[4] = __builtin_amdgcn_mfma_f32_16x16x32_bf16(pf1, onesf, o[4], 0, 0, 0);
        }
    }

    // epilogue: l lives in o[4][r] of lanes col==0; broadcast within quad
    #pragma unroll
    for (int r = 0; r < 4; r++) {
        float lv = __shfl(o[4][r], lane & 48);
        float inv = 1.0f / lv;
        int sq = qb + w * 16 + quad * 4 + r;
        size_t base = ((size_t)(bh >> 4) * SS + sq) * DD + (size_t)(bh & 15) * DHH;
        #pragma unroll
        for (int dt = 0; dt < 4; dt++)
            O[base + dt * 16 + col] = f2bf(o[dt][r] * inv);
    }
}

// ---------------------------------------------------------------- launch
extern "C" void kernel_launch(void* const* d_in, const int* in_sizes, int n_in,
                              void* d_out, int out_size, void* d_ws, size_t ws_size,
                              hipStream_t stream) {
    (void)in_sizes; (void)n_in; (void)out_size; (void)ws_size;
    const float* x  = (const float*)d_in[0];
    const float* Wq = (const float*)d_in[2];
    const float* bq = (const float*)d_in[3];
    const float* Wk = (const float*)d_in[4];
    const float* bk = (const float*)d_in[5];
    const float* Wv = (const float*)d_in[6];
    const float* bv = (const float*)d_in[7];
    const float* Wo = (const float*)d_in[8];
    const float* bo = (const float*)d_in[9];
    float* out = (float*)d_out;

    // ws (40 MB): x_bf/O | Q | K | V^T | Wt x4
    char* ws = (char*)d_ws;
    unsigned short* xbf = (unsigned short*)(ws);
    unsigned short* qws = (unsigned short*)(ws + ((size_t)8  << 20));
    unsigned short* kws = (unsigned short*)(ws + ((size_t)16 << 20));
    unsigned short* vws = (unsigned short*)(ws + ((size_t)24 << 20));
    unsigned short* wt  = (unsigned short*)(ws + ((size_t)32 << 20));
    unsigned short* ows = xbf;   // O overwrites x_bf (dead after QKV GEMM)

    prep<<<dim3(5120), 256, 0, stream>>>(x, Wq, Wk, Wv, Wo, xbf, wt);
    gemm_qkv<<<dim3(16, 32), 256, 0, stream>>>(xbf, wt, bq, bk, bv,
                                               qws, kws, vws);
    attn<<<dim3(1024), 256, 0, stream>>>(qws, kws, vws, ows);
    gemm_out<<<dim3(8, 32), 256, 0, stream>>>(ows, wt + (size_t)3 * 1024 * 1024,
                                              bo, out);
}